// Round 9
// baseline (512.818 us; speedup 1.0000x reference)
//
#include <hip/hip_runtime.h>

typedef unsigned short u16;
typedef __bf16 bf16x8 __attribute__((ext_vector_type(8)));
typedef float f32x4 __attribute__((ext_vector_type(4)));

#define TOK 8192
#define DM 1024
#define HID 4096
#define RH 1024
#define NE 8
#define MAX_SLOTS 18432  // 16384 slots + 8*256 padding

__device__ __forceinline__ u16 f2bf(float f) {
  union { float f; unsigned u; } v; v.f = f;
  unsigned u = v.u;
  return (u16)((u + 0x7fffu + ((u >> 16) & 1u)) >> 16);  // RNE
}
__device__ __forceinline__ float bf2f(u16 h) {
  union { unsigned u; float f; } v; v.u = ((unsigned)h) << 16; return v.f;
}

struct alignas(8) U16x4 { u16 x, y, z, w; };
__device__ __forceinline__ U16x4 cvt4(float4 v) {
  return U16x4{f2bf(v.x), f2bf(v.y), f2bf(v.z), f2bf(v.w)};
}

// counts live at cc[e*16] (one cache line per expert, low atomic contention);
// cursors at cc[128+e].

// ---------------- mega-prep: casts/packs + slot init + ROUTER(+counts) ----------------
__global__ __launch_bounds__(256) void k_prep(
    const float4* __restrict__ x, const float4* __restrict__ sw1, const float4* __restrict__ sw2,
    const float4* __restrict__ sw3, const float4* __restrict__ w12, const float4* __restrict__ w3,
    const float* __restrict__ xs, const float* __restrict__ rw, const float* __restrict__ bias,
    U16x4* __restrict__ xb, U16x4* __restrict__ wshu, U16x4* __restrict__ wshd,
    U16x4* __restrict__ wru, U16x4* __restrict__ wrd,
    int* __restrict__ slot_token, float* __restrict__ slot_gate, int* __restrict__ cc,
    int* __restrict__ tok_e, float* __restrict__ tok_g) {
  int b = blockIdx.x, tid = threadIdx.x;
  if (b < 8192) {                       // x cast (8192x1024 fp32 -> bf16)
    int i = b * 256 + tid;
    xb[i] = cvt4(x[i]);
  } else if (b < 16384) {               // shared-up pack: row 2n=w1[n], 2n+1=w2[n]
    int i = (b - 8192) * 256 + tid;
    int row = i >> 8, c4 = i & 255;
    const float4* src = (row & 1) ? sw2 : sw1;
    wshu[(size_t)row * 256 + c4] = cvt4(src[(size_t)(row >> 1) * 256 + c4]);
  } else if (b < 20480) {               // shared-down cast (1024x4096)
    int i = (b - 16384) * 256 + tid;
    wshd[i] = cvt4(sw3[i]);
  } else if (b < 36864) {               // routed-up pack per expert
    int i = (b - 20480) * 256 + tid;
    int c4 = i & 255, row = (i >> 8) & 2047, e = i >> 19;
    int srow = (row & 1) ? (1024 + (row >> 1)) : (row >> 1);
    wru[((size_t)e * 2048 + row) * 256 + c4] = cvt4(w12[((size_t)e * 2048 + srow) * 256 + c4]);
  } else if (b < 45056) {               // routed-down cast (8x1024x1024)
    int i = (b - 36864) * 256 + tid;
    wrd[i] = cvt4(w3[i]);
  } else if (b < 45128) {               // slot init
    int i = (b - 45056) * 256 + tid;
    if (i < MAX_SLOTS) { slot_token[i] = 0; slot_gate[i] = 0.f; }
  } else {                              // router: 256 blocks, 8 tokens per wave, LDS hist
    __shared__ int cnt[NE];
    int wave = tid >> 6, lane = tid & 63;
    if (tid < NE) cnt[tid] = 0;
    __syncthreads();
    int base_t = ((b - 45128) * 4 + wave) * 8;
#pragma unroll 1
    for (int k = 0; k < 8; k++) {
      int t = base_t + k;
      const float4* xr = (const float4*)(xs + (size_t)t * DM) + lane * 4;
      float4 xv[4];
#pragma unroll
      for (int j = 0; j < 4; j++) xv[j] = xr[j];
      float p[NE];
#pragma unroll
      for (int e = 0; e < NE; e++) {
        const float4* wr = (const float4*)(rw + (size_t)e * DM) + lane * 4;
        float s = 0.f;
#pragma unroll
        for (int j = 0; j < 4; j++) {
          float4 w = wr[j];
          s += xv[j].x * w.x + xv[j].y * w.y + xv[j].z * w.z + xv[j].w * w.w;
        }
        p[e] = s;
      }
#pragma unroll
      for (int e = 0; e < NE; e++) {
        float v = p[e];
#pragma unroll
        for (int off = 32; off; off >>= 1) v += __shfl_xor(v, off, 64);
        p[e] = v;
      }
      if (lane == 0) {
        float sc[NE];
#pragma unroll
        for (int e = 0; e < NE; e++) sc[e] = 1.f / (1.f + __expf(-p[e]));
        int e0 = 0; float b0 = sc[0] + bias[0];
#pragma unroll
        for (int e = 1; e < NE; e++) { float v = sc[e] + bias[e]; if (v > b0) { b0 = v; e0 = e; } }
        int e1 = -1; float b1 = -1e30f;
#pragma unroll
        for (int e = 0; e < NE; e++) { if (e == e0) continue; float v = sc[e] + bias[e]; if (v > b1) { b1 = v; e1 = e; } }
        tok_e[t * 2] = e0; tok_e[t * 2 + 1] = e1;
        tok_g[t * 2] = sc[e0]; tok_g[t * 2 + 1] = sc[e1];
        atomicAdd(&cnt[e0], 1);
        atomicAdd(&cnt[e1], 1);
      }
    }
    __syncthreads();
    if (tid < NE) atomicAdd(&cc[tid * 16], cnt[tid]);  // spread: 1 line per expert
  }
}

// ---------------- assign: two-level; offsets computed inline from strided counts ----------------
__global__ __launch_bounds__(256) void k_assign(const int* __restrict__ tok_e, const float* __restrict__ tok_g,
                                                const int* __restrict__ cc, int* __restrict__ cursors,
                                                int* __restrict__ slot_token, float* __restrict__ slot_gate,
                                                int* __restrict__ token_slots) {
  __shared__ int lcnt[NE];
  __shared__ int base[NE];
  __shared__ int offs_s[NE];
  int tid = threadIdx.x;
  if (tid < NE) lcnt[tid] = 0;
  __syncthreads();
  int t = blockIdx.x * 256 + tid;
  int e0 = tok_e[t * 2], e1 = tok_e[t * 2 + 1];
  int r0 = atomicAdd(&lcnt[e0], 1);
  int r1 = atomicAdd(&lcnt[e1], 1);
  __syncthreads();
  if (tid == 0) {
    int o = 0;
#pragma unroll
    for (int e = 0; e < NE; e++) { offs_s[e] = o; o += (cc[e * 16] + 255) & ~255; }
  }
  if (tid < NE) base[tid] = atomicAdd(&cursors[tid], lcnt[tid]);
  __syncthreads();
  int s0 = offs_s[e0] + base[e0] + r0;
  int s1 = offs_s[e1] + base[e1] + r1;
  slot_token[s0] = t;
  slot_gate[s0] = tok_g[t * 2];
  token_slots[t * 2] = s0;
  slot_token[s1] = t;
  slot_gate[s1] = tok_g[t * 2 + 1];
  token_slots[t * 2 + 1] = s1;
}

#define AS1(p) ((__attribute__((address_space(1))) void*)(p))
#define AS3(p) ((__attribute__((address_space(3))) void*)(p))

// ---------------- merged UP-GEMM (m97 128x128): shared-up + routed-up in one dispatch ----
__global__ __launch_bounds__(256, 2) void gemm_up(
    const u16* __restrict__ xb,
    const u16* __restrict__ wshu, const u16* __restrict__ wru,
    u16* __restrict__ g, u16* __restrict__ gr,
    const int* __restrict__ slot_token, const float* __restrict__ slot_gate,
    const int* __restrict__ cc) {
  __shared__ alignas(16) u16 Al[128 * 64];
  __shared__ alignas(16) u16 Bl[128 * 64];
  const int tid = threadIdx.x;
  const int lane = tid & 63, wave = tid >> 6;
  const int bid = blockIdx.x;
  const bool routed = bid >= 4096;
  int nt, mt, m0g, ldc;
  const u16* Bp;
  u16* Cb;
  if (!routed) {
    nt = bid & 63; mt = bid >> 6;
    m0g = mt * 128;
    Bp = wshu; Cb = g; ldc = HID;
  } else {
    int r = bid - 4096;
    int e = r >> 11, rr = r & 2047;
    nt = rr & 15; mt = rr >> 4;
    int cnt = cc[e << 4];
    if (mt * 128 >= cnt) return;  // block-uniform early exit (before any barrier)
    int off = 0;
#pragma unroll
    for (int q = 0; q < NE; q++) if (q < e) off += (cc[q << 4] + 255) & ~255;
    m0g = off + mt * 128;
    Bp = wru + (size_t)e * (2 * RH * DM);
    Cb = gr; ldc = RH;
  }
  const int n0 = nt * 128;

  const u16* aSrc[4];
  const u16* bSrc[4];
#pragma unroll
  for (int j = 0; j < 4; j++) {
    int r = wave * 32 + j * 8 + (lane >> 3);
    int cg = (lane & 7) ^ (r & 7);
    int arow = m0g + r;
    if (routed) arow = slot_token[arow];
    aSrc[j] = xb + (size_t)arow * DM + cg * 8;
    bSrc[j] = Bp + (size_t)(n0 + r) * DM + cg * 8;
  }

  f32x4 acc[4][4];
#pragma unroll
  for (int m = 0; m < 4; m++)
#pragma unroll
    for (int n = 0; n < 4; n++) acc[m][n] = (f32x4){0.f, 0.f, 0.f, 0.f};

  const int wm = wave >> 1, wn = wave & 1;
  for (int kt = 0; kt < DM / 64; ++kt) {
    __syncthreads();
#pragma unroll
    for (int j = 0; j < 4; j++) {
      __builtin_amdgcn_global_load_lds(AS1(aSrc[j]), AS3(&Al[(wave * 32 + j * 8) * 64]), 16, 0, 0);
      __builtin_amdgcn_global_load_lds(AS1(bSrc[j]), AS3(&Bl[(wave * 32 + j * 8) * 64]), 16, 0, 0);
      aSrc[j] += 64; bSrc[j] += 64;
    }
    asm volatile("s_waitcnt vmcnt(0)" ::: "memory");
    __syncthreads();
#pragma unroll
    for (int ks = 0; ks < 2; ++ks) {
      bf16x8 af[4], bfv[4];
#pragma unroll
      for (int m = 0; m < 4; m++) {
        int row = wm * 64 + m * 16 + (lane & 15);
        int cg = ((lane >> 4) + ks * 4) ^ (row & 7);
        af[m] = *(const bf16x8*)&Al[row * 64 + cg * 8];
      }
#pragma unroll
      for (int n = 0; n < 4; n++) {
        int row = wn * 64 + n * 16 + (lane & 15);
        int cg = ((lane >> 4) + ks * 4) ^ (row & 7);
        bfv[n] = *(const bf16x8*)&Bl[row * 64 + cg * 8];
      }
#pragma unroll
      for (int m = 0; m < 4; m++)
#pragma unroll
        for (int n = 0; n < 4; n++)
          acc[m][n] = __builtin_amdgcn_mfma_f32_16x16x32_bf16(af[m], bfv[n], acc[m][n], 0, 0, 0);
    }
  }

  // SwiGLU-pair epilogue. C/D layout: col = lane&15, row = (lane>>4)*4 + reg
#pragma unroll
  for (int m = 0; m < 4; m++) {
#pragma unroll
    for (int r = 0; r < 4; r++) {
      int grow = m0g + wm * 64 + m * 16 + (lane >> 4) * 4 + r;
      float gate = 1.f;
      if (routed) gate = slot_gate[grow];  // 0 on padded slots -> zeros
#pragma unroll
      for (int n = 0; n < 4; n++) {
        float v = acc[m][n][r];
        float o = __shfl_xor(v, 1, 64);  // partner column (all lanes execute)
        if (!(lane & 1)) {               // even col = h1, odd = h2
          float gv = v / (1.f + __expf(-v)) * o * gate;
          int col = (n0 + wn * 64 + n * 16 + (lane & 15)) >> 1;
          Cb[(size_t)grow * ldc + col] = f2bf(gv);
        }
      }
    }
  }
}

// ---------------- GEMM (m97 128x128): down-projections ----------------
// EPI 3: plain bf16 store
// EPI 4: fp32 store + fused routed-combine: out = acc + rp[slot0] + rp[slot1]
template<int EPI, bool GROUPED>
__global__ __launch_bounds__(256, 2) void gemm_bt(
    const u16* __restrict__ A, int lda,
    const u16* __restrict__ B, int ldb, size_t strideB,
    void* __restrict__ Cout, int ldc,
    int K,
    const int* __restrict__ slot_token,   // EPI4: token_slots
    const int* __restrict__ cc,
    const u16* __restrict__ rpb) {        // EPI4: routed per-slot output (bf16)
  __shared__ alignas(16) u16 Al[128 * 64];
  __shared__ alignas(16) u16 Bl[128 * 64];
  const int tid = threadIdx.x;
  const int lane = tid & 63, wave = tid >> 6;
  const int nt = blockIdx.x, mt = blockIdx.y;
  int m0g;
  const u16* Bp = B;
  if (GROUPED) {
    const int e = blockIdx.z;
    int cnt = cc[e << 4];
    if (mt * 128 >= cnt) return;  // block-uniform early exit
    int off = 0;
#pragma unroll
    for (int q = 0; q < NE; q++) if (q < e) off += (cc[q << 4] + 255) & ~255;
    m0g = off + mt * 128;
    Bp += (size_t)e * strideB;
  } else {
    m0g = mt * 128;
  }
  const int n0 = nt * 128;

  const u16* aSrc[4];
  const u16* bSrc[4];
#pragma unroll
  for (int j = 0; j < 4; j++) {
    int r = wave * 32 + j * 8 + (lane >> 3);
    int cg = (lane & 7) ^ (r & 7);
    int arow = m0g + r;
    aSrc[j] = A + (size_t)arow * lda + cg * 8;
    bSrc[j] = Bp + (size_t)(n0 + r) * ldb + cg * 8;
  }

  f32x4 acc[4][4];
#pragma unroll
  for (int m = 0; m < 4; m++)
#pragma unroll
    for (int n = 0; n < 4; n++) acc[m][n] = (f32x4){0.f, 0.f, 0.f, 0.f};

  const int wm = wave >> 1, wn = wave & 1;
  const int KT = K >> 6;
  for (int kt = 0; kt < KT; ++kt) {
    __syncthreads();
#pragma unroll
    for (int j = 0; j < 4; j++) {
      __builtin_amdgcn_global_load_lds(AS1(aSrc[j]), AS3(&Al[(wave * 32 + j * 8) * 64]), 16, 0, 0);
      __builtin_amdgcn_global_load_lds(AS1(bSrc[j]), AS3(&Bl[(wave * 32 + j * 8) * 64]), 16, 0, 0);
      aSrc[j] += 64; bSrc[j] += 64;
    }
    asm volatile("s_waitcnt vmcnt(0)" ::: "memory");
    __syncthreads();
#pragma unroll
    for (int ks = 0; ks < 2; ++ks) {
      bf16x8 af[4], bfv[4];
#pragma unroll
      for (int m = 0; m < 4; m++) {
        int row = wm * 64 + m * 16 + (lane & 15);
        int cg = ((lane >> 4) + ks * 4) ^ (row & 7);
        af[m] = *(const bf16x8*)&Al[row * 64 + cg * 8];
      }
#pragma unroll
      for (int n = 0; n < 4; n++) {
        int row = wn * 64 + n * 16 + (lane & 15);
        int cg = ((lane >> 4) + ks * 4) ^ (row & 7);
        bfv[n] = *(const bf16x8*)&Bl[row * 64 + cg * 8];
      }
#pragma unroll
      for (int m = 0; m < 4; m++)
#pragma unroll
        for (int n = 0; n < 4; n++)
          acc[m][n] = __builtin_amdgcn_mfma_f32_16x16x32_bf16(af[m], bfv[n], acc[m][n], 0, 0, 0);
    }
  }

  if (EPI == 4) {
    float* Cf = (float*)Cout;
#pragma unroll
    for (int m = 0; m < 4; m++) {
#pragma unroll
      for (int r = 0; r < 4; r++) {
        int grow = m0g + wm * 64 + m * 16 + (lane >> 4) * 4 + r;
        int s0 = slot_token[grow * 2], s1 = slot_token[grow * 2 + 1];
        const u16* p0 = rpb + (size_t)s0 * DM;
        const u16* p1 = rpb + (size_t)s1 * DM;
#pragma unroll
        for (int n = 0; n < 4; n++) {
          int col = n0 + wn * 64 + n * 16 + (lane & 15);
          float v = acc[m][n][r] + bf2f(p0[col]) + bf2f(p1[col]);
          Cf[(size_t)grow * ldc + col] = v;
        }
      }
    }
  } else {  // EPI == 3
    u16* Cb = (u16*)Cout;
#pragma unroll
    for (int m = 0; m < 4; m++) {
#pragma unroll
      for (int r = 0; r < 4; r++) {
        int grow = m0g + wm * 64 + m * 16 + (lane >> 4) * 4 + r;
#pragma unroll
        for (int n = 0; n < 4; n++) {
          int col = n0 + wn * 64 + n * 16 + (lane & 15);
          Cb[(size_t)grow * ldc + col] = f2bf(acc[m][n][r]);
        }
      }
    }
  }
}

extern "C" void kernel_launch(void* const* d_in, const int* in_sizes, int n_in,
                              void* d_out, int out_size, void* d_ws, size_t ws_size,
                              hipStream_t stream) {
  const float* x    = (const float*)d_in[0];
  const float* w12  = (const float*)d_in[1];
  const float* w3   = (const float*)d_in[2];
  const float* sw1  = (const float*)d_in[3];
  const float* sw2  = (const float*)d_in[4];
  const float* sw3  = (const float*)d_in[5];
  const float* rw   = (const float*)d_in[6];
  const float* bias = (const float*)d_in[7];
  float* out = (float*)d_out;

  char* ws = (char*)d_ws;
  size_t off = 0;
  auto alloc = [&](size_t bytes) -> void* {
    void* p = ws + off;
    off += (bytes + 255) & ~(size_t)255;
    return p;
  };
  u16* xb   = (u16*)alloc((size_t)TOK * DM * 2);           // x bf16
  u16* wshu = (u16*)alloc((size_t)2 * HID * DM * 2);       // shared up, interleaved
  u16* wshd = (u16*)alloc((size_t)DM * HID * 2);           // shared down
  u16* wru  = (u16*)alloc((size_t)NE * 2 * RH * DM * 2);   // routed up, interleaved
  u16* wrd  = (u16*)alloc((size_t)NE * DM * RH * 2);       // routed down
  u16* gr   = (u16*)alloc((size_t)MAX_SLOTS * RH * 2);     // gated routed hidden (slot-major)
  u16* g    = (u16*)alloc((size_t)TOK * HID * 2);          // shared gated hidden
  u16* rp   = (u16*)alloc((size_t)MAX_SLOTS * DM * 2);     // routed per-slot output (bf16)
  int* cc      = (int*)alloc(1024);                        // counts[e*16] + cursors at +128
  int* cursors = cc + 128;
  int* tok_e   = (int*)alloc((size_t)TOK * 2 * 4);
  float* tok_g = (float*)alloc((size_t)TOK * 2 * 4);
  int* slot_token  = (int*)alloc((size_t)MAX_SLOTS * 4);
  float* slot_gate = (float*)alloc((size_t)MAX_SLOTS * 4);
  int* token_slots = (int*)alloc((size_t)TOK * 2 * 4);
  (void)in_sizes; (void)n_in; (void)out_size; (void)ws_size;

  hipMemsetAsync(cc, 0, 1024, stream);
  // prep (+router +counts): 45056 cast/pack + 72 slot-init + 256 router blocks
  k_prep<<<45384, 256, 0, stream>>>((const float4*)x, (const float4*)sw1, (const float4*)sw2,
                                    (const float4*)sw3, (const float4*)w12, (const float4*)w3,
                                    x, rw, bias,
                                    (U16x4*)xb, (U16x4*)wshu, (U16x4*)wshd, (U16x4*)wru, (U16x4*)wrd,
                                    slot_token, slot_gate, cc, tok_e, tok_g);
  k_assign<<<TOK / 256, 256, 0, stream>>>(tok_e, tok_g, cc, cursors, slot_token, slot_gate, token_slots);

  // merged up-GEMMs: shared-up (4096 blocks) + routed-up (8x2048 blocks), one dispatch
  gemm_up<<<4096 + 8 * 2048, 256, 0, stream>>>(
      xb, wshu, wru, g, gr, slot_token, slot_gate, cc);

  // routed down (grouped, slot-contiguous): per-expert (cnt x 1024 x 1024) -> rp bf16
  gemm_bt<3, true><<<dim3(8, 128, 8), 256, 0, stream>>>(
      gr, RH, wrd, RH, (size_t)DM * RH, rp, DM, RH, nullptr, cc, nullptr);
  // shared down + fused combine: (8192 x 1024 x 4096) + rp[slot0]+rp[slot1] -> out fp32
  gemm_bt<4, false><<<dim3(8, 64, 1), 256, 0, stream>>>(
      g, HID, wshd, HID, 0, out, DM, HID, token_slots, nullptr, rp);
}

// Round 10
// 496.270 us; speedup vs baseline: 1.0333x; 1.0333x over previous
//
#include <hip/hip_runtime.h>

typedef unsigned short u16;
typedef __bf16 bf16x8 __attribute__((ext_vector_type(8)));
typedef float f32x4 __attribute__((ext_vector_type(4)));

#define TOK 8192
#define DM 1024
#define HID 4096
#define RH 1024
#define NE 8
#define MAX_SLOTS 18432  // 16384 slots + 8*256 padding

__device__ __forceinline__ u16 f2bf(float f) {
  union { float f; unsigned u; } v; v.f = f;
  unsigned u = v.u;
  return (u16)((u + 0x7fffu + ((u >> 16) & 1u)) >> 16);  // RNE
}
__device__ __forceinline__ float bf2f(u16 h) {
  union { unsigned u; float f; } v; v.u = ((unsigned)h) << 16; return v.f;
}

struct alignas(8) U16x4 { u16 x, y, z, w; };
__device__ __forceinline__ U16x4 cvt4(float4 v) {
  return U16x4{f2bf(v.x), f2bf(v.y), f2bf(v.z), f2bf(v.w)};
}

// ---------------- mega-prep: casts/packs + slot init + cc zero + ROUTER ----------------
__global__ __launch_bounds__(256) void k_prep(
    const float4* __restrict__ x, const float4* __restrict__ sw1, const float4* __restrict__ sw2,
    const float4* __restrict__ sw3, const float4* __restrict__ w12, const float4* __restrict__ w3,
    const float* __restrict__ xs, const float* __restrict__ rw, const float* __restrict__ bias,
    U16x4* __restrict__ xb, U16x4* __restrict__ wshu, U16x4* __restrict__ wshd,
    U16x4* __restrict__ wru, U16x4* __restrict__ wrd,
    int* __restrict__ slot_token, float* __restrict__ slot_gate, int* __restrict__ cc,
    int* __restrict__ tok_e, float* __restrict__ tok_g) {
  int b = blockIdx.x, tid = threadIdx.x;
  if (b < 8192) {                       // x cast (8192x1024 fp32 -> bf16)
    int i = b * 256 + tid;
    xb[i] = cvt4(x[i]);
  } else if (b < 16384) {               // shared-up pack: row 2n=w1[n], 2n+1=w2[n]
    int i = (b - 8192) * 256 + tid;
    int row = i >> 8, c4 = i & 255;
    const float4* src = (row & 1) ? sw2 : sw1;
    wshu[(size_t)row * 256 + c4] = cvt4(src[(size_t)(row >> 1) * 256 + c4]);
  } else if (b < 20480) {               // shared-down cast (1024x4096)
    int i = (b - 16384) * 256 + tid;
    wshd[i] = cvt4(sw3[i]);
  } else if (b < 36864) {               // routed-up pack per expert
    int i = (b - 20480) * 256 + tid;
    int c4 = i & 255, row = (i >> 8) & 2047, e = i >> 19;
    int srow = (row & 1) ? (1024 + (row >> 1)) : (row >> 1);
    wru[((size_t)e * 2048 + row) * 256 + c4] = cvt4(w12[((size_t)e * 2048 + srow) * 256 + c4]);
  } else if (b < 45056) {               // routed-down cast (8x1024x1024)
    int i = (b - 36864) * 256 + tid;
    wrd[i] = cvt4(w3[i]);
  } else if (b < 45128) {               // slot init (+ cc zero in first block)
    int i = (b - 45056) * 256 + tid;
    if (i < MAX_SLOTS) { slot_token[i] = 0; slot_gate[i] = 0.f; }
    if (b == 45056 && tid < 16) cc[tid] = 0;
  } else {                              // router: one wave per token, no atomics
    int wave = tid >> 6, lane = tid & 63;
    int t = (b - 45128) * 4 + wave;
    const float4* xr = (const float4*)(xs + (size_t)t * DM) + lane * 4;
    float4 xv[4];
#pragma unroll
    for (int j = 0; j < 4; j++) xv[j] = xr[j];
    float p[NE];
#pragma unroll
    for (int e = 0; e < NE; e++) {
      const float4* wr = (const float4*)(rw + (size_t)e * DM) + lane * 4;
      float s = 0.f;
#pragma unroll
      for (int j = 0; j < 4; j++) {
        float4 w = wr[j];
        s += xv[j].x * w.x + xv[j].y * w.y + xv[j].z * w.z + xv[j].w * w.w;
      }
      p[e] = s;
    }
#pragma unroll
    for (int e = 0; e < NE; e++) {
      float v = p[e];
#pragma unroll
      for (int off = 32; off; off >>= 1) v += __shfl_xor(v, off, 64);
      p[e] = v;
    }
    if (lane == 0) {
      float sc[NE];
#pragma unroll
      for (int e = 0; e < NE; e++) sc[e] = 1.f / (1.f + __expf(-p[e]));
      int e0 = 0; float b0 = sc[0] + bias[0];
#pragma unroll
      for (int e = 1; e < NE; e++) { float v = sc[e] + bias[e]; if (v > b0) { b0 = v; e0 = e; } }
      int e1 = -1; float b1 = -1e30f;
#pragma unroll
      for (int e = 0; e < NE; e++) { if (e == e0) continue; float v = sc[e] + bias[e]; if (v > b1) { b1 = v; e1 = e; } }
      tok_e[t * 2] = e0; tok_e[t * 2 + 1] = e1;
      tok_g[t * 2] = sc[e0]; tok_g[t * 2 + 1] = sc[e1];
    }
  }
}

// ---------------- count: per-block LDS histogram, 8 global atomics/block ----------------
__global__ __launch_bounds__(256) void k_count(const int* __restrict__ tok_e, int* __restrict__ counts) {
  __shared__ int cnt[NE];
  int tid = threadIdx.x;
  if (tid < NE) cnt[tid] = 0;
  __syncthreads();
  int t = blockIdx.x * 256 + tid;
  atomicAdd(&cnt[tok_e[t * 2]], 1);
  atomicAdd(&cnt[tok_e[t * 2 + 1]], 1);
  __syncthreads();
  if (tid < NE) atomicAdd(&counts[tid], cnt[tid]);
}

// ---------------- assign: two-level; offsets computed inline from counts ----------------
__global__ __launch_bounds__(256) void k_assign(const int* __restrict__ tok_e, const float* __restrict__ tok_g,
                                                const int* __restrict__ counts, int* __restrict__ cursors,
                                                int* __restrict__ slot_token, float* __restrict__ slot_gate,
                                                int* __restrict__ token_slots) {
  __shared__ int lcnt[NE];
  __shared__ int base[NE];
  __shared__ int offs_s[NE];
  int tid = threadIdx.x;
  if (tid < NE) lcnt[tid] = 0;
  __syncthreads();
  int t = blockIdx.x * 256 + tid;
  int e0 = tok_e[t * 2], e1 = tok_e[t * 2 + 1];
  int r0 = atomicAdd(&lcnt[e0], 1);
  int r1 = atomicAdd(&lcnt[e1], 1);
  __syncthreads();
  if (tid == 0) {
    int o = 0;
#pragma unroll
    for (int e = 0; e < NE; e++) { offs_s[e] = o; o += (counts[e] + 255) & ~255; }
  }
  if (tid < NE) base[tid] = atomicAdd(&cursors[tid], lcnt[tid]);
  __syncthreads();
  int s0 = offs_s[e0] + base[e0] + r0;
  int s1 = offs_s[e1] + base[e1] + r1;
  slot_token[s0] = t;
  slot_gate[s0] = tok_g[t * 2];
  token_slots[t * 2] = s0;
  slot_token[s1] = t;
  slot_gate[s1] = tok_g[t * 2 + 1];
  token_slots[t * 2 + 1] = s1;
}

#define AS1(p) ((__attribute__((address_space(1))) void*)(p))
#define AS3(p) ((__attribute__((address_space(3))) void*)(p))

// ---------------- merged UP-GEMM (m97 128x128): shared-up + routed-up in one dispatch ----
// 1D grid: bid < 4096 -> shared-up tile (nt=bid&63, mt=bid>>6), K=1024, B=wshu -> g
//          bid >= 4096 -> routed expert e=(bid-4096)>>11, nt=rr&15, mt=rr>>4, B=wru[e] -> gr
// Both use the SwiGLU-pair epilogue (even col=h1, odd=h2); routed applies gate + A-gather.
__global__ __launch_bounds__(256, 2) void gemm_up(
    const u16* __restrict__ xb,
    const u16* __restrict__ wshu, const u16* __restrict__ wru,
    u16* __restrict__ g, u16* __restrict__ gr,
    const int* __restrict__ slot_token, const float* __restrict__ slot_gate,
    const int* __restrict__ counts) {
  __shared__ alignas(16) u16 Al[128 * 64];
  __shared__ alignas(16) u16 Bl[128 * 64];
  const int tid = threadIdx.x;
  const int lane = tid & 63, wave = tid >> 6;
  const int bid = blockIdx.x;
  const bool routed = bid >= 4096;
  int nt, mt, m0g, ldc;
  const u16* Bp;
  u16* Cb;
  if (!routed) {
    nt = bid & 63; mt = bid >> 6;
    m0g = mt * 128;
    Bp = wshu; Cb = g; ldc = HID;
  } else {
    int r = bid - 4096;
    int e = r >> 11, rr = r & 2047;
    nt = rr & 15; mt = rr >> 4;
    int cnt = counts[e];
    if (mt * 128 >= cnt) return;  // block-uniform early exit (before any barrier)
    int off = 0;
#pragma unroll
    for (int q = 0; q < NE; q++) if (q < e) off += (counts[q] + 255) & ~255;
    m0g = off + mt * 128;
    Bp = wru + (size_t)e * (2 * RH * DM);
    Cb = gr; ldc = RH;
  }
  const int n0 = nt * 128;

  // staging source pointers; XOR swizzle pre-applied on global colgroup
  const u16* aSrc[4];
  const u16* bSrc[4];
#pragma unroll
  for (int j = 0; j < 4; j++) {
    int r = wave * 32 + j * 8 + (lane >> 3);
    int cg = (lane & 7) ^ (r & 7);
    int arow = m0g + r;
    if (routed) arow = slot_token[arow];
    aSrc[j] = xb + (size_t)arow * DM + cg * 8;
    bSrc[j] = Bp + (size_t)(n0 + r) * DM + cg * 8;
  }

  f32x4 acc[4][4];
#pragma unroll
  for (int m = 0; m < 4; m++)
#pragma unroll
    for (int n = 0; n < 4; n++) acc[m][n] = (f32x4){0.f, 0.f, 0.f, 0.f};

  const int wm = wave >> 1, wn = wave & 1;
  for (int kt = 0; kt < DM / 64; ++kt) {
    __syncthreads();
#pragma unroll
    for (int j = 0; j < 4; j++) {
      __builtin_amdgcn_global_load_lds(AS1(aSrc[j]), AS3(&Al[(wave * 32 + j * 8) * 64]), 16, 0, 0);
      __builtin_amdgcn_global_load_lds(AS1(bSrc[j]), AS3(&Bl[(wave * 32 + j * 8) * 64]), 16, 0, 0);
      aSrc[j] += 64; bSrc[j] += 64;
    }
    asm volatile("s_waitcnt vmcnt(0)" ::: "memory");
    __syncthreads();
#pragma unroll
    for (int ks = 0; ks < 2; ++ks) {
      bf16x8 af[4], bfv[4];
#pragma unroll
      for (int m = 0; m < 4; m++) {
        int row = wm * 64 + m * 16 + (lane & 15);
        int cg = ((lane >> 4) + ks * 4) ^ (row & 7);
        af[m] = *(const bf16x8*)&Al[row * 64 + cg * 8];
      }
#pragma unroll
      for (int n = 0; n < 4; n++) {
        int row = wn * 64 + n * 16 + (lane & 15);
        int cg = ((lane >> 4) + ks * 4) ^ (row & 7);
        bfv[n] = *(const bf16x8*)&Bl[row * 64 + cg * 8];
      }
#pragma unroll
      for (int m = 0; m < 4; m++)
#pragma unroll
        for (int n = 0; n < 4; n++)
          acc[m][n] = __builtin_amdgcn_mfma_f32_16x16x32_bf16(af[m], bfv[n], acc[m][n], 0, 0, 0);
    }
  }

  // SwiGLU-pair epilogue. C/D layout: col = lane&15, row = (lane>>4)*4 + reg
#pragma unroll
  for (int m = 0; m < 4; m++) {
#pragma unroll
    for (int r = 0; r < 4; r++) {
      int grow = m0g + wm * 64 + m * 16 + (lane >> 4) * 4 + r;
      float gate = 1.f;
      if (routed) gate = slot_gate[grow];  // 0 on padded slots -> zeros
#pragma unroll
      for (int n = 0; n < 4; n++) {
        float v = acc[m][n][r];
        float o = __shfl_xor(v, 1, 64);  // partner column (all lanes execute)
        if (!(lane & 1)) {               // even col = h1, odd = h2
          float gv = v / (1.f + __expf(-v)) * o * gate;
          int col = (n0 + wn * 64 + n * 16 + (lane & 15)) >> 1;
          Cb[(size_t)grow * ldc + col] = f2bf(gv);
        }
      }
    }
  }
}

// ---------------- GEMM (m97 128x128): down-projections ----------------
// EPI 3: plain bf16 store
// EPI 4: fp32 store + fused routed-combine: out = acc + rp[slot0] + rp[slot1]
template<int EPI, bool GROUPED>
__global__ __launch_bounds__(256, 2) void gemm_bt(
    const u16* __restrict__ A, int lda,
    const u16* __restrict__ B, int ldb, size_t strideB,
    void* __restrict__ Cout, int ldc,
    int K,
    const int* __restrict__ slot_token,   // EPI4: token_slots
    const int* __restrict__ counts,
    const u16* __restrict__ rpb) {        // EPI4: routed per-slot output (bf16)
  __shared__ alignas(16) u16 Al[128 * 64];
  __shared__ alignas(16) u16 Bl[128 * 64];
  const int tid = threadIdx.x;
  const int lane = tid & 63, wave = tid >> 6;
  const int nt = blockIdx.x, mt = blockIdx.y;
  int m0g;
  const u16* Bp = B;
  if (GROUPED) {
    const int e = blockIdx.z;
    int cnt = counts[e];
    if (mt * 128 >= cnt) return;  // block-uniform early exit
    int off = 0;
#pragma unroll
    for (int q = 0; q < NE; q++) if (q < e) off += (counts[q] + 255) & ~255;
    m0g = off + mt * 128;
    Bp += (size_t)e * strideB;
  } else {
    m0g = mt * 128;
  }
  const int n0 = nt * 128;

  const u16* aSrc[4];
  const u16* bSrc[4];
#pragma unroll
  for (int j = 0; j < 4; j++) {
    int r = wave * 32 + j * 8 + (lane >> 3);
    int cg = (lane & 7) ^ (r & 7);
    int arow = m0g + r;
    aSrc[j] = A + (size_t)arow * lda + cg * 8;
    bSrc[j] = Bp + (size_t)(n0 + r) * ldb + cg * 8;
  }

  f32x4 acc[4][4];
#pragma unroll
  for (int m = 0; m < 4; m++)
#pragma unroll
    for (int n = 0; n < 4; n++) acc[m][n] = (f32x4){0.f, 0.f, 0.f, 0.f};

  const int wm = wave >> 1, wn = wave & 1;
  const int KT = K >> 6;
  for (int kt = 0; kt < KT; ++kt) {
    __syncthreads();
#pragma unroll
    for (int j = 0; j < 4; j++) {
      __builtin_amdgcn_global_load_lds(AS1(aSrc[j]), AS3(&Al[(wave * 32 + j * 8) * 64]), 16, 0, 0);
      __builtin_amdgcn_global_load_lds(AS1(bSrc[j]), AS3(&Bl[(wave * 32 + j * 8) * 64]), 16, 0, 0);
      aSrc[j] += 64; bSrc[j] += 64;
    }
    asm volatile("s_waitcnt vmcnt(0)" ::: "memory");
    __syncthreads();
#pragma unroll
    for (int ks = 0; ks < 2; ++ks) {
      bf16x8 af[4], bfv[4];
#pragma unroll
      for (int m = 0; m < 4; m++) {
        int row = wm * 64 + m * 16 + (lane & 15);
        int cg = ((lane >> 4) + ks * 4) ^ (row & 7);
        af[m] = *(const bf16x8*)&Al[row * 64 + cg * 8];
      }
#pragma unroll
      for (int n = 0; n < 4; n++) {
        int row = wn * 64 + n * 16 + (lane & 15);
        int cg = ((lane >> 4) + ks * 4) ^ (row & 7);
        bfv[n] = *(const bf16x8*)&Bl[row * 64 + cg * 8];
      }
#pragma unroll
      for (int m = 0; m < 4; m++)
#pragma unroll
        for (int n = 0; n < 4; n++)
          acc[m][n] = __builtin_amdgcn_mfma_f32_16x16x32_bf16(af[m], bfv[n], acc[m][n], 0, 0, 0);
    }
  }

  if (EPI == 4) {
    float* Cf = (float*)Cout;
#pragma unroll
    for (int m = 0; m < 4; m++) {
#pragma unroll
      for (int r = 0; r < 4; r++) {
        int grow = m0g + wm * 64 + m * 16 + (lane >> 4) * 4 + r;
        int s0 = slot_token[grow * 2], s1 = slot_token[grow * 2 + 1];
        const u16* p0 = rpb + (size_t)s0 * DM;
        const u16* p1 = rpb + (size_t)s1 * DM;
#pragma unroll
        for (int n = 0; n < 4; n++) {
          int col = n0 + wn * 64 + n * 16 + (lane & 15);
          float v = acc[m][n][r] + bf2f(p0[col]) + bf2f(p1[col]);
          Cf[(size_t)grow * ldc + col] = v;
        }
      }
    }
  } else {  // EPI == 3
    u16* Cb = (u16*)Cout;
#pragma unroll
    for (int m = 0; m < 4; m++) {
#pragma unroll
      for (int r = 0; r < 4; r++) {
        int grow = m0g + wm * 64 + m * 16 + (lane >> 4) * 4 + r;
#pragma unroll
        for (int n = 0; n < 4; n++) {
          int col = n0 + wn * 64 + n * 16 + (lane & 15);
          Cb[(size_t)grow * ldc + col] = f2bf(acc[m][n][r]);
        }
      }
    }
  }
}

extern "C" void kernel_launch(void* const* d_in, const int* in_sizes, int n_in,
                              void* d_out, int out_size, void* d_ws, size_t ws_size,
                              hipStream_t stream) {
  const float* x    = (const float*)d_in[0];
  const float* w12  = (const float*)d_in[1];
  const float* w3   = (const float*)d_in[2];
  const float* sw1  = (const float*)d_in[3];
  const float* sw2  = (const float*)d_in[4];
  const float* sw3  = (const float*)d_in[5];
  const float* rw   = (const float*)d_in[6];
  const float* bias = (const float*)d_in[7];
  float* out = (float*)d_out;

  char* ws = (char*)d_ws;
  size_t off = 0;
  auto alloc = [&](size_t bytes) -> void* {
    void* p = ws + off;
    off += (bytes + 255) & ~(size_t)255;
    return p;
  };
  u16* xb   = (u16*)alloc((size_t)TOK * DM * 2);           // x bf16
  u16* wshu = (u16*)alloc((size_t)2 * HID * DM * 2);       // shared up, interleaved
  u16* wshd = (u16*)alloc((size_t)DM * HID * 2);           // shared down
  u16* wru  = (u16*)alloc((size_t)NE * 2 * RH * DM * 2);   // routed up, interleaved
  u16* wrd  = (u16*)alloc((size_t)NE * DM * RH * 2);       // routed down
  u16* gr   = (u16*)alloc((size_t)MAX_SLOTS * RH * 2);     // gated routed hidden (slot-major)
  u16* g    = (u16*)alloc((size_t)TOK * HID * 2);          // shared gated hidden
  u16* rp   = (u16*)alloc((size_t)MAX_SLOTS * DM * 2);     // routed per-slot output (bf16)
  int* cc      = (int*)alloc(64);                          // counts[8] + cursors[8]
  int* counts  = cc;
  int* cursors = cc + 8;
  int* tok_e   = (int*)alloc((size_t)TOK * 2 * 4);
  float* tok_g = (float*)alloc((size_t)TOK * 2 * 4);
  int* slot_token  = (int*)alloc((size_t)MAX_SLOTS * 4);
  float* slot_gate = (float*)alloc((size_t)MAX_SLOTS * 4);
  int* token_slots = (int*)alloc((size_t)TOK * 2 * 4);
  (void)in_sizes; (void)n_in; (void)out_size; (void)ws_size;

  // prep (+router +cc zero): 45056 cast/pack + 72 slot-init + 2048 router blocks
  k_prep<<<47176, 256, 0, stream>>>((const float4*)x, (const float4*)sw1, (const float4*)sw2,
                                    (const float4*)sw3, (const float4*)w12, (const float4*)w3,
                                    x, rw, bias,
                                    (U16x4*)xb, (U16x4*)wshu, (U16x4*)wshd, (U16x4*)wru, (U16x4*)wrd,
                                    slot_token, slot_gate, cc, tok_e, tok_g);
  k_count<<<TOK / 256, 256, 0, stream>>>(tok_e, counts);
  k_assign<<<TOK / 256, 256, 0, stream>>>(tok_e, tok_g, counts, cursors, slot_token, slot_gate, token_slots);

  // merged up-GEMMs: shared-up (4096 blocks) + routed-up (8x2048 blocks), one dispatch
  gemm_up<<<4096 + 8 * 2048, 256, 0, stream>>>(
      xb, wshu, wru, g, gr, slot_token, slot_gate, counts);

  // routed down (grouped, slot-contiguous): per-expert (cnt x 1024 x 1024) -> rp bf16
  gemm_bt<3, true><<<dim3(8, 128, 8), 256, 0, stream>>>(
      gr, RH, wrd, RH, (size_t)DM * RH, rp, DM, RH, nullptr, counts, nullptr);
  // shared down + fused combine: (8192 x 1024 x 4096) + rp[slot0]+rp[slot1] -> out fp32
  gemm_bt<4, false><<<dim3(8, 64, 1), 256, 0, stream>>>(
      g, HID, wshd, HID, 0, out, DM, HID, token_slots, nullptr, rp);
}